// Round 6
// baseline (665.278 us; speedup 1.0000x reference)
//
#include <hip/hip_runtime.h>

#define N_NODES 100000
#define N_EDGES 800000
#define DV 64
#define DE 32
#define DU 32
#define H 128

#define NTILES 12500      // N_EDGES / 64

typedef short bf16x8 __attribute__((ext_vector_type(8)));
typedef unsigned short u16;
typedef u16 u16x8 __attribute__((ext_vector_type(8)));
typedef float f32x4 __attribute__((ext_vector_type(4)));

// ---- workspace layout (bytes) ----
#define OFF_ESUM 0            // [128][16] f32 padded sums
#define OFF_VSUM 8192         // [128][16] f32
#define OFF_BIAS 16384        // [256] f32: folded b1e' (0..127), b1n' (128..255)
#define OFF_PART 17408        // [512] int scan partials
#define OFF_WBUF 19456        // [77824] u16 weights
#define OFF_DEG  175104       // [100000] int degree -> cursor
#define OFF_SE   575104       // [800000] int2 {src, orig edge id} per bucket slot
#define OFF_DSTP 6975104      // [800000] int dst per bucket slot
// total ~10.2 MB

// weight sub-offsets (u16 elements within wbuf)
#define W1ET_OFF 0            // [128][160]  (u rows folded into bias)
#define W2ET_OFF 20480        // [128][128]
#define W1NT_OFF 36864        // [128][192]  (u rows folded into bias)
#define W2NT_OFF 61440        // [128][128]
#define WBUF_ELEMS 77824

#define NPART 391             // ceil(100000/256)

__device__ inline u16 f2bf(float x) {
  union { float f; unsigned u; } c; c.f = x;
  unsigned r = c.u + 0x7FFFu + ((c.u >> 16) & 1u);   // round-to-nearest-even
  return (u16)(r >> 16);
}

__global__ void prep_weights(const float* __restrict__ W1e, const float* __restrict__ W2e,
                             const float* __restrict__ W1n, const float* __restrict__ W2n,
                             u16* __restrict__ wbuf) {
  int i = blockIdx.x * blockDim.x + threadIdx.x;
  if (i < 20480) {                     // W1e^T [128][160]
    int j = i / 160, k = i - j * 160;
    wbuf[W1ET_OFF + i] = f2bf(W1e[k * H + j]);
  } else if (i < 36864) {              // W2e^T [128][128]
    int t = i - 20480; int j = t >> 7, k = t & 127;
    wbuf[i] = f2bf(W2e[k * H + j]);
  } else if (i < 61440) {              // W1n^T [128][192]
    int t = i - 36864; int j = t / 192, k = t - j * 192;
    wbuf[i] = f2bf(W1n[k * H + j]);
  } else if (i < WBUF_ELEMS) {         // W2n^T [128][128]
    int t = i - 61440; int j = t >> 7, k = t & 127;
    wbuf[i] = f2bf(W2n[k * H + j]);
  }
}

// fold u@W1u into layer-1 biases (u is a single global row: node_idx/edge_idx all 0)
__global__ void prep_bias(const float* __restrict__ uattr,
                          const float* __restrict__ W1e, const float* __restrict__ b1e,
                          const float* __restrict__ W1n, const float* __restrict__ b1n,
                          float* __restrict__ bias) {
  int t = threadIdx.x;   // 128
  float be = b1e[t];
  float bn = b1n[t];
  for (int k = 0; k < DU; ++k) {
    float uk = uattr[k];
    be += uk * W1e[(2 * DV + DE + k) * H + t];   // u rows start at 160
    bn += uk * W1n[(DV + H + k) * H + t];        // u rows start at 192
  }
  bias[t] = be;
  bias[128 + t] = bn;
}

// ---------------- CSR build ----------------
__global__ void degree_kernel(const int* __restrict__ edges, int* __restrict__ deg) {
  int i = blockIdx.x * 256 + threadIdx.x;
  if (i < N_EDGES) atomicAdd(&deg[edges[N_EDGES + i]], 1);
}

__global__ void scan_part(const int* __restrict__ deg, int* __restrict__ part) {
  int i = blockIdx.x * 256 + threadIdx.x;
  int v = (i < N_NODES) ? deg[i] : 0;
#pragma unroll
  for (int m = 1; m < 64; m <<= 1) v += __shfl_xor(v, m);
  __shared__ int s[4];
  if ((threadIdx.x & 63) == 0) s[threadIdx.x >> 6] = v;
  __syncthreads();
  if (threadIdx.x == 0) part[blockIdx.x] = s[0] + s[1] + s[2] + s[3];
}

__global__ void scan_top(int* __restrict__ part) {
  __shared__ int s[512];
  int t = threadIdx.x;
  s[t] = (t < NPART) ? part[t] : 0;
  __syncthreads();
  for (int d = 1; d < 512; d <<= 1) {
    int v = (t >= d) ? s[t - d] : 0;
    __syncthreads();
    s[t] += v;
    __syncthreads();
  }
  if (t < NPART) part[t] = (t == 0) ? 0 : s[t - 1];   // exclusive
}

__global__ void scan_down(const int* __restrict__ part, int* __restrict__ deg_cursor) {
  __shared__ int s[256];
  int b = blockIdx.x, t = threadIdx.x;
  int i = b * 256 + t;
  int v = (i < N_NODES) ? deg_cursor[i] : 0;
  s[t] = v;
  __syncthreads();
  for (int d = 1; d < 256; d <<= 1) {
    int u = (t >= d) ? s[t - d] : 0;
    __syncthreads();
    s[t] += u;
    __syncthreads();
  }
  int excl = s[t] - v + part[b];
  if (i < N_NODES) deg_cursor[i] = excl;   // cursor = row start
}

__global__ void fill_kernel(const int* __restrict__ edges, int* __restrict__ cursor,
                            int2* __restrict__ se, int* __restrict__ dstP) {
  int i = blockIdx.x * 256 + threadIdx.x;
  if (i < N_EDGES) {
    int s = edges[i];
    int d = edges[N_EDGES + i];
    int pos = atomicAdd(&cursor[d], 1);
    se[pos] = make_int2(s, i);
    dstP[pos] = d;
  }
}

// ---- edge kernel: tiles of 64 bucket-ordered edges; fused aggregation ----
__global__ __launch_bounds__(256, 4) void edge_kernel(
    const float* __restrict__ node_attr, const float* __restrict__ edge_attr,
    const u16* __restrict__ wbuf, const float* __restrict__ bias_f,
    const float* __restrict__ b2,
    const int2* __restrict__ se, const int* __restrict__ dstP,
    float* __restrict__ e_out, float* __restrict__ agg, float* __restrict__ esum_p)
{
  __shared__ __align__(16) char smem[37888];
  u16 (*X)[164]    = (u16(*)[164])smem;               // 20992 B (stride 82 dw: conflict-free)
  u16 (*Hs)[132]   = (u16(*)[132])(smem + 20992);     // 16896 B (stride 66 dw: conflict-free)
  float (*OT)[132] = (float(*)[132])smem;             // 33792 B overlay (after l2)
  __shared__ int sSrc[64], sEid[64], sDst[64];

  const int tid = threadIdx.x;
  const int wave = tid >> 6, lane = tid & 63;
  const int l15 = lane & 15, lg = lane >> 4;
  const int wc = wave * 32;

  // bijective XCD-chunk swizzle (m204)
  int b = blockIdx.x;
  const int q = NTILES / 8, r8 = NTILES % 8;
  int xcd = b & 7, pos = b >> 3;
  long t = (xcd < r8 ? xcd * (q + 1) : r8 * (q + 1) + (xcd - r8) * q) + pos;
  const long i0 = t * 64;

  if (tid < 64)        { int2 v = se[i0 + tid]; sSrc[tid] = v.x; sEid[tid] = v.y; }
  else if (tid < 128)  sDst[tid - 64] = dstP[i0 + (tid - 64)];

  // layer-1 weight slice in registers
  bf16x8 w1[5][2];
  {
    const u16* w1t = wbuf + W1ET_OFF;
#pragma unroll
    for (int cf = 0; cf < 2; ++cf) {
      const u16* p1 = w1t + (wc + cf * 16 + l15) * 160 + lg * 8;
#pragma unroll
      for (int ks = 0; ks < 5; ++ks) w1[ks][cf] = *(const bf16x8*)(p1 + ks * 32);
    }
  }
  float bias1[2] = { bias_f[wc + l15], bias_f[wc + 16 + l15] };

  __syncthreads();

  // stage X: 64 rows x 160 cols of bf16 -> 1280 chunks, 5/thread
#pragma unroll
  for (int it = 0; it < 5; ++it) {
    int ch = tid + it * 256;
    int r = ch / 20, g = ch - r * 20;
    int col = g * 8;
    const float* src;
    if (col < 64)        src = node_attr + (long)sSrc[r] * DV + col;
    else if (col < 128)  src = node_attr + (long)sDst[r] * DV + (col - 64);
    else                 src = edge_attr + (long)sEid[r] * DE + (col - 128);
    float4 f0 = *(const float4*)src;
    float4 f1 = *(const float4*)(src + 4);
    u16x8 p;
    p[0] = f2bf(f0.x); p[1] = f2bf(f0.y); p[2] = f2bf(f0.z); p[3] = f2bf(f0.w);
    p[4] = f2bf(f1.x); p[5] = f2bf(f1.y); p[6] = f2bf(f1.z); p[7] = f2bf(f1.w);
    *(u16x8*)&X[r][col] = p;
  }

  __syncthreads();

  f32x4 acc[4][2];
#pragma unroll
  for (int rf = 0; rf < 4; ++rf)
#pragma unroll
    for (int cf = 0; cf < 2; ++cf)
#pragma unroll
      for (int j = 0; j < 4; ++j) acc[rf][cf][j] = 0.f;

  // layer 1: [64,160] @ [160,128]
#pragma unroll
  for (int ks = 0; ks < 5; ++ks) {
#pragma unroll
    for (int rf = 0; rf < 4; ++rf) {
      bf16x8 a = *(const bf16x8*)&X[rf * 16 + l15][ks * 32 + lg * 8];
      acc[rf][0] = __builtin_amdgcn_mfma_f32_16x16x32_bf16(a, w1[ks][0], acc[rf][0], 0, 0, 0);
      acc[rf][1] = __builtin_amdgcn_mfma_f32_16x16x32_bf16(a, w1[ks][1], acc[rf][1], 0, 0, 0);
    }
  }

  // load layer-2 weights now (overlaps; keeps peak VGPR down)
  bf16x8 w2[4][2];
  {
    const u16* w2t = wbuf + W2ET_OFF;
#pragma unroll
    for (int cf = 0; cf < 2; ++cf) {
      const u16* p2 = w2t + (wc + cf * 16 + l15) * 128 + lg * 8;
#pragma unroll
      for (int ks = 0; ks < 4; ++ks) w2[ks][cf] = *(const bf16x8*)(p2 + ks * 32);
    }
  }
  float bias2[2] = { b2[wc + l15], b2[wc + 16 + l15] };

#pragma unroll
  for (int rf = 0; rf < 4; ++rf)
#pragma unroll
    for (int cf = 0; cf < 2; ++cf)
#pragma unroll
      for (int j = 0; j < 4; ++j) {
        float hv = acc[rf][cf][j] + bias1[cf];
        hv = hv > 0.f ? hv : 0.f;
        Hs[rf * 16 + lg * 4 + j][wc + cf * 16 + l15] = f2bf(hv);
      }

  __syncthreads();

#pragma unroll
  for (int rf = 0; rf < 4; ++rf)
#pragma unroll
    for (int cf = 0; cf < 2; ++cf)
#pragma unroll
      for (int j = 0; j < 4; ++j) acc[rf][cf][j] = 0.f;

  // layer 2: [64,128] @ [128,128]
#pragma unroll
  for (int ks = 0; ks < 4; ++ks) {
#pragma unroll
    for (int rf = 0; rf < 4; ++rf) {
      bf16x8 a = *(const bf16x8*)&Hs[rf * 16 + l15][ks * 32 + lg * 8];
      acc[rf][0] = __builtin_amdgcn_mfma_f32_16x16x32_bf16(a, w2[ks][0], acc[rf][0], 0, 0, 0);
      acc[rf][1] = __builtin_amdgcn_mfma_f32_16x16x32_bf16(a, w2[ks][1], acc[rf][1], 0, 0, 0);
    }
  }

  __syncthreads();   // Hs reads done before OT overwrite

  float es0 = 0.f, es1 = 0.f;
#pragma unroll
  for (int rf = 0; rf < 4; ++rf) {
#pragma unroll
    for (int cf = 0; cf < 2; ++cf) {
#pragma unroll
      for (int j = 0; j < 4; ++j) {
        float v = acc[rf][cf][j] + bias2[cf];
        OT[rf * 16 + lg * 4 + j][wc + cf * 16 + l15] = v;
        if (cf == 0) es0 += v; else es1 += v;
      }
    }
  }

  __syncthreads();   // OT ready

  // scattered e_out row stores: all 256 threads, fire-and-forget
#pragma unroll
  for (int i = 0; i < 8; ++i) {
    int ch = tid + i * 256;
    int r = ch >> 5, c4 = ch & 31;
    float4 f = *(const float4*)&OT[r][c4 * 4];
    *(float4*)(e_out + (long)sEid[r] * H + c4 * 4) = f;
  }

  // fused aggregation: half-tile segmented sum (128 cols x 2 halves; uniform branches)
  {
    const int c = tid & 127;
    const int rlo = (tid >> 7) * 32;
    float sum = 0.f;
    int runStart = rlo;
#pragma unroll 8
    for (int r = rlo; r < rlo + 32; ++r) {
      sum += OT[r][c];
      bool bnd = (r == rlo + 31) || (sDst[r + 1] != sDst[r]);
      if (bnd) {
        float* p = &agg[(long)sDst[r] * H + c];
        if (runStart == rlo || r == rlo + 31) atomicAdd(p, sum);  // may span boundary
        else *p = sum;                                            // complete run
        sum = 0.f; runStart = r + 1;
      }
    }
  }

#pragma unroll
  for (int m = 16; m < 64; m <<= 1) { es0 += __shfl_xor(es0, m); es1 += __shfl_xor(es1, m); }
  if (lane < 16) {
    atomicAdd(&esum_p[(wc + lane) * 16], es0);
    atomicAdd(&esum_p[(wc + 16 + lane) * 16], es1);
  }
}

// ---- node kernel: pure sequential-read MLP; agg read in place from v region ----
__global__ __launch_bounds__(256, 3) void node_kernel(
    const float* __restrict__ node_attr, const u16* __restrict__ wbuf,
    const float* __restrict__ bias_f, const float* __restrict__ b2,
    float* __restrict__ vio, float* __restrict__ vsum_p)
{
  __shared__ __align__(16) u16 X[64][196];    // 192 cols + pad (stride 98 dw: conflict-free)
  __shared__ __align__(16) u16 Hs[64][132];

  const int tid = threadIdx.x;
  const int wave = tid >> 6, lane = tid & 63;
  const int l15 = lane & 15, lg = lane >> 4;
  const long n0 = (long)blockIdx.x * 64;
  const int wc = wave * 32;

  // stage X: cols 0-63 node_attr, 64-191 agg (in v region): 1536 chunks, 6/thread
#pragma unroll
  for (int it = 0; it < 6; ++it) {
    int ch = tid + it * 256;
    int r = ch / 24, g = ch - r * 24;
    int col = g * 8;
    long n = n0 + r; if (n >= N_NODES) n = N_NODES - 1;   // clamp tail
    const float* src;
    if (col < 64)  src = node_attr + n * DV + col;
    else           src = vio + n * H + (col - 64);
    float4 f0 = *(const float4*)src;
    float4 f1 = *(const float4*)(src + 4);
    u16x8 p;
    p[0] = f2bf(f0.x); p[1] = f2bf(f0.y); p[2] = f2bf(f0.z); p[3] = f2bf(f0.w);
    p[4] = f2bf(f1.x); p[5] = f2bf(f1.y); p[6] = f2bf(f1.z); p[7] = f2bf(f1.w);
    *(u16x8*)&X[r][col] = p;
  }

  // per-wave weight slices
  bf16x8 w1[6][2], w2[4][2];
  {
    const u16* w1t = wbuf + W1NT_OFF;
    const u16* w2t = wbuf + W2NT_OFF;
#pragma unroll
    for (int cf = 0; cf < 2; ++cf) {
      const u16* p1 = w1t + (wc + cf * 16 + l15) * 192 + lg * 8;
#pragma unroll
      for (int ks = 0; ks < 6; ++ks) w1[ks][cf] = *(const bf16x8*)(p1 + ks * 32);
      const u16* p2 = w2t + (wc + cf * 16 + l15) * 128 + lg * 8;
#pragma unroll
      for (int ks = 0; ks < 4; ++ks) w2[ks][cf] = *(const bf16x8*)(p2 + ks * 32);
    }
  }

  __syncthreads();

  f32x4 acc[4][2];
#pragma unroll
  for (int rf = 0; rf < 4; ++rf)
#pragma unroll
    for (int cf = 0; cf < 2; ++cf)
#pragma unroll
      for (int j = 0; j < 4; ++j) acc[rf][cf][j] = 0.f;

#pragma unroll
  for (int ks = 0; ks < 6; ++ks) {
#pragma unroll
    for (int rf = 0; rf < 4; ++rf) {
      bf16x8 a = *(const bf16x8*)&X[rf * 16 + l15][ks * 32 + lg * 8];
      acc[rf][0] = __builtin_amdgcn_mfma_f32_16x16x32_bf16(a, w1[ks][0], acc[rf][0], 0, 0, 0);
      acc[rf][1] = __builtin_amdgcn_mfma_f32_16x16x32_bf16(a, w1[ks][1], acc[rf][1], 0, 0, 0);
    }
  }

  float bias1[2] = { bias_f[128 + wc + l15], bias_f[128 + wc + 16 + l15] };
#pragma unroll
  for (int rf = 0; rf < 4; ++rf)
#pragma unroll
    for (int cf = 0; cf < 2; ++cf)
#pragma unroll
      for (int j = 0; j < 4; ++j) {
        float hv = acc[rf][cf][j] + bias1[cf];
        hv = hv > 0.f ? hv : 0.f;
        Hs[rf * 16 + lg * 4 + j][wc + cf * 16 + l15] = f2bf(hv);
      }

  __syncthreads();

#pragma unroll
  for (int rf = 0; rf < 4; ++rf)
#pragma unroll
    for (int cf = 0; cf < 2; ++cf)
#pragma unroll
      for (int j = 0; j < 4; ++j) acc[rf][cf][j] = 0.f;

#pragma unroll
  for (int ks = 0; ks < 4; ++ks) {
#pragma unroll
    for (int rf = 0; rf < 4; ++rf) {
      bf16x8 a = *(const bf16x8*)&Hs[rf * 16 + l15][ks * 32 + lg * 8];
      acc[rf][0] = __builtin_amdgcn_mfma_f32_16x16x32_bf16(a, w2[ks][0], acc[rf][0], 0, 0, 0);
      acc[rf][1] = __builtin_amdgcn_mfma_f32_16x16x32_bf16(a, w2[ks][1], acc[rf][1], 0, 0, 0);
    }
  }

  float bias2[2] = { b2[wc + l15], b2[wc + 16 + l15] };
  float vs0 = 0.f, vs1 = 0.f;
#pragma unroll
  for (int rf = 0; rf < 4; ++rf) {
#pragma unroll
    for (int cf = 0; cf < 2; ++cf) {
      int colg = wc + cf * 16 + l15;
#pragma unroll
      for (int j = 0; j < 4; ++j) {
        int r = rf * 16 + lg * 4 + j;
        long n = n0 + r;
        if (n < N_NODES) {
          float v = acc[rf][cf][j] + bias2[cf];
          vio[n * H + colg] = v;   // in-place overwrite of agg (reads done pre-barrier)
          if (cf == 0) vs0 += v; else vs1 += v;
        }
      }
    }
  }
#pragma unroll
  for (int m = 16; m < 64; m <<= 1) { vs0 += __shfl_xor(vs0, m); vs1 += __shfl_xor(vs1, m); }
  if (lane < 16) {
    atomicAdd(&vsum_p[(wc + lane) * 16], vs0);
    atomicAdd(&vsum_p[(wc + 16 + lane) * 16], vs1);
  }
}

// ---------------- global kernel: G=1, f32 precision ----------------
__global__ void global_kernel(const float* __restrict__ uattr,
    const float* __restrict__ W1g, const float* __restrict__ b1g,
    const float* __restrict__ W2g, const float* __restrict__ b2g,
    const float* __restrict__ esum_p, const float* __restrict__ vsum_p,
    float* __restrict__ g_out)
{
  __shared__ float gin[288];
  __shared__ float hbuf[128];
  int t = threadIdx.x;   // 128 threads
  gin[t]       = vsum_p[t * 16] * (1.f / (float)N_NODES);
  gin[128 + t] = esum_p[t * 16] * (1.f / (float)N_EDGES);
  if (t < 32) gin[256 + t] = uattr[t];
  __syncthreads();
  float a = b1g[t];
  for (int k = 0; k < 288; ++k) a += gin[k] * W1g[k * H + t];
  hbuf[t] = fmaxf(a, 0.f);
  __syncthreads();
  float b = b2g[t];
  for (int k = 0; k < 128; ++k) b += hbuf[k] * W2g[k * H + t];
  g_out[t] = b;
}

extern "C" void kernel_launch(void* const* d_in, const int* in_sizes, int n_in,
                              void* d_out, int out_size, void* d_ws, size_t ws_size,
                              hipStream_t stream) {
  const float* node_attr = (const float*)d_in[0];
  const int*   edges     = (const int*)d_in[1];
  const float* edge_attr = (const float*)d_in[2];
  const float* uattr     = (const float*)d_in[3];
  const float* W1e = (const float*)d_in[6];  const float* b1e = (const float*)d_in[7];
  const float* W2e = (const float*)d_in[8];  const float* b2e = (const float*)d_in[9];
  const float* W1n = (const float*)d_in[10]; const float* b1n = (const float*)d_in[11];
  const float* W2n = (const float*)d_in[12]; const float* b2n = (const float*)d_in[13];
  const float* W1g = (const float*)d_in[14]; const float* b1g = (const float*)d_in[15];
  const float* W2g = (const float*)d_in[16]; const float* b2g = (const float*)d_in[17];

  float* out   = (float*)d_out;
  float* v_out = out;                                          // [N,H] (agg first)
  float* e_out = out + (long)N_NODES * H;                      // [E,H]
  float* g_out = out + (long)N_NODES * H + (long)N_EDGES * H;  // [G,H]

  char* ws = (char*)d_ws;
  float* esum_p = (float*)(ws + OFF_ESUM);
  float* vsum_p = (float*)(ws + OFF_VSUM);
  float* bias_f = (float*)(ws + OFF_BIAS);
  int*   part   = (int*)(ws + OFF_PART);
  u16*   wbuf   = (u16*)(ws + OFF_WBUF);
  int*   deg    = (int*)(ws + OFF_DEG);     // becomes cursor after scan_down
  int2*  se     = (int2*)(ws + OFF_SE);
  int*   dstP   = (int*)(ws + OFF_DSTP);

  hipMemsetAsync(ws, 0, 16384, stream);                   // esum_p + vsum_p
  hipMemsetAsync(deg, 0, N_NODES * sizeof(int), stream);  // degrees
  hipMemsetAsync(v_out, 0, (size_t)N_NODES * H * sizeof(float), stream);  // agg init

  prep_weights<<<WBUF_ELEMS / 256, 256, 0, stream>>>(W1e, W2e, W1n, W2n, wbuf);
  prep_bias<<<1, 128, 0, stream>>>(uattr, W1e, b1e, W1n, b1n, bias_f);
  degree_kernel<<<(N_EDGES + 255) / 256, 256, 0, stream>>>(edges, deg);
  scan_part<<<NPART, 256, 0, stream>>>(deg, part);
  scan_top<<<1, 512, 0, stream>>>(part);
  scan_down<<<NPART, 256, 0, stream>>>(part, deg);
  fill_kernel<<<(N_EDGES + 255) / 256, 256, 0, stream>>>(edges, deg, se, dstP);

  edge_kernel<<<NTILES, 256, 0, stream>>>(node_attr, edge_attr, wbuf,
                                          bias_f, b2e, se, dstP,
                                          e_out, v_out, esum_p);
  node_kernel<<<(N_NODES + 63) / 64, 256, 0, stream>>>(node_attr, wbuf,
                                                       bias_f, b2n, v_out, vsum_p);
  global_kernel<<<1, 128, 0, stream>>>(uattr, W1g, b1g, W2g, b2g, esum_p, vsum_p, g_out);
}

// Round 7
// 626.526 us; speedup vs baseline: 1.0619x; 1.0619x over previous
//
#include <hip/hip_runtime.h>

#define N_NODES 100000
#define N_EDGES 800000
#define DV 64
#define DE 32
#define DU 32
#define H 128

#define ETILE 128
#define NTILES_E (N_EDGES / ETILE)   // 6250

typedef short bf16x8 __attribute__((ext_vector_type(8)));
typedef unsigned short u16;
typedef u16 u16x8 __attribute__((ext_vector_type(8)));
typedef float f32x4 __attribute__((ext_vector_type(4)));

// ---- workspace layout (bytes) ----
#define OFF_ESUM 0            // [128][16] f32 padded sums
#define OFF_VSUM 8192         // [128][16] f32
#define OFF_BIAS 16384        // [256] f32: folded b1e' (0..127), b1n' (128..255)
#define OFF_PART 17408        // [512] int scan partials
#define OFF_WBUF 19456        // [77824] u16 weights
#define OFF_DEG  175104       // [100000] int degree -> cursor (row end after fill)
#define OFF_OFFS 575104       // [100000] int CSR row starts
#define OFF_BUCK 975104       // [800000] int edge ids grouped by dst
// total ~4.18 MB

// weight sub-offsets (u16 elements within wbuf)
#define W1ET_OFF 0            // [128][160]  (u rows folded into bias)
#define W2ET_OFF 20480        // [128][128]
#define W1NT_OFF 36864        // [128][192]  (u rows folded into bias)
#define W2NT_OFF 61440        // [128][128]
#define WBUF_ELEMS 77824

#define NPART 391             // ceil(100000/256)

__device__ inline u16 f2bf(float x) {
  union { float f; unsigned u; } c; c.f = x;
  unsigned r = c.u + 0x7FFFu + ((c.u >> 16) & 1u);   // round-to-nearest-even
  return (u16)(r >> 16);
}

__global__ void prep_weights(const float* __restrict__ W1e, const float* __restrict__ W2e,
                             const float* __restrict__ W1n, const float* __restrict__ W2n,
                             u16* __restrict__ wbuf) {
  int i = blockIdx.x * blockDim.x + threadIdx.x;
  if (i < 20480) {                     // W1e^T [128][160]
    int j = i / 160, k = i - j * 160;
    wbuf[W1ET_OFF + i] = f2bf(W1e[k * H + j]);
  } else if (i < 36864) {              // W2e^T [128][128]
    int t = i - 20480; int j = t >> 7, k = t & 127;
    wbuf[i] = f2bf(W2e[k * H + j]);
  } else if (i < 61440) {              // W1n^T [128][192]
    int t = i - 36864; int j = t / 192, k = t - j * 192;
    wbuf[i] = f2bf(W1n[k * H + j]);
  } else if (i < WBUF_ELEMS) {         // W2n^T [128][128]
    int t = i - 61440; int j = t >> 7, k = t & 127;
    wbuf[i] = f2bf(W2n[k * H + j]);
  }
}

// fold u@W1u into layer-1 biases (node_idx/edge_idx all 0, G=1)
__global__ void prep_bias(const float* __restrict__ uattr,
                          const float* __restrict__ W1e, const float* __restrict__ b1e,
                          const float* __restrict__ W1n, const float* __restrict__ b1n,
                          float* __restrict__ bias) {
  int t = threadIdx.x;   // 128
  float be = b1e[t];
  float bn = b1n[t];
  for (int k = 0; k < DU; ++k) {
    float uk = uattr[k];
    be += uk * W1e[(2 * DV + DE + k) * H + t];
    bn += uk * W1n[(DV + H + k) * H + t];
  }
  bias[t] = be;
  bias[128 + t] = bn;
}

// ---------------- CSR build ----------------
__global__ void degree_kernel(const int* __restrict__ edges, int* __restrict__ deg) {
  int i = blockIdx.x * 256 + threadIdx.x;
  if (i < N_EDGES) atomicAdd(&deg[edges[N_EDGES + i]], 1);
}

__global__ void scan_part(const int* __restrict__ deg, int* __restrict__ part) {
  int i = blockIdx.x * 256 + threadIdx.x;
  int v = (i < N_NODES) ? deg[i] : 0;
#pragma unroll
  for (int m = 1; m < 64; m <<= 1) v += __shfl_xor(v, m);
  __shared__ int s[4];
  if ((threadIdx.x & 63) == 0) s[threadIdx.x >> 6] = v;
  __syncthreads();
  if (threadIdx.x == 0) part[blockIdx.x] = s[0] + s[1] + s[2] + s[3];
}

__global__ void scan_top(int* __restrict__ part) {
  __shared__ int s[512];
  int t = threadIdx.x;
  s[t] = (t < NPART) ? part[t] : 0;
  __syncthreads();
  for (int d = 1; d < 512; d <<= 1) {
    int v = (t >= d) ? s[t - d] : 0;
    __syncthreads();
    s[t] += v;
    __syncthreads();
  }
  if (t < NPART) part[t] = (t == 0) ? 0 : s[t - 1];   // exclusive
}

__global__ void scan_down(const int* __restrict__ part, int* __restrict__ deg_cursor,
                          int* __restrict__ offsets) {
  __shared__ int s[256];
  int b = blockIdx.x, t = threadIdx.x;
  int i = b * 256 + t;
  int v = (i < N_NODES) ? deg_cursor[i] : 0;
  s[t] = v;
  __syncthreads();
  for (int d = 1; d < 256; d <<= 1) {
    int u = (t >= d) ? s[t - d] : 0;
    __syncthreads();
    s[t] += u;
    __syncthreads();
  }
  int excl = s[t] - v + part[b];
  if (i < N_NODES) { offsets[i] = excl; deg_cursor[i] = excl; }  // cursor = start
}

__global__ void fill_kernel(const int* __restrict__ edges, int* __restrict__ cursor,
                            int* __restrict__ bucket) {
  int i = blockIdx.x * 256 + threadIdx.x;
  if (i < N_EDGES) {
    int d = edges[N_EDGES + i];
    int pos = atomicAdd(&cursor[d], 1);
    bucket[pos] = i;
  }
}

// ---- edge kernel: 128 original-order edges/block, 512 threads (8 waves) ----
// contiguous edge_attr reads + contiguous e_out writes; only src/dst gathers scatter
__global__ __launch_bounds__(512, 2) void edge_kernel(
    const float* __restrict__ node_attr, const int* __restrict__ edges,
    const float* __restrict__ edge_attr,
    const u16* __restrict__ wbuf, const float* __restrict__ bias_f,
    const float* __restrict__ b2,
    float* __restrict__ e_out, float* __restrict__ esum_p)
{
  __shared__ __align__(16) char smem[75776];
  u16 (*X)[164]    = (u16(*)[164])smem;               // 41984 B (stride 82 dw)
  u16 (*Hs)[132]   = (u16(*)[132])(smem + 41984);     // 33792 B (stride 66 dw)
  float (*OT)[132] = (float(*)[132])smem;             // 67584 B overlay (after l2)
  __shared__ int sSrc[128], sDst[128];

  const int tid = threadIdx.x;
  const int wave = tid >> 6, lane = tid & 63;
  const int l15 = lane & 15, lg = lane >> 4;
  const int wc = (wave & 3) * 32;      // col group
  const int rh = (wave >> 2) * 64;     // row half
  const long e0 = (long)blockIdx.x * ETILE;

  if (tid < 128)       sSrc[tid]       = edges[e0 + tid];
  else if (tid < 256)  sDst[tid - 128] = edges[(long)N_EDGES + e0 + (tid - 128)];

  // layer-1 weight slice in registers
  bf16x8 w1[5][2];
  {
    const u16* w1t = wbuf + W1ET_OFF;
#pragma unroll
    for (int cf = 0; cf < 2; ++cf) {
      const u16* p1 = w1t + (wc + cf * 16 + l15) * 160 + lg * 8;
#pragma unroll
      for (int ks = 0; ks < 5; ++ks) w1[ks][cf] = *(const bf16x8*)(p1 + ks * 32);
    }
  }
  float bias1[2] = { bias_f[wc + l15], bias_f[wc + 16 + l15] };

  __syncthreads();

  // stage X: 128 rows x 160 cols -> 2560 chunks of 8 cols, 5/thread.
  // hoist ALL loads before ALL LDS writes (160B/thread in flight)
  {
    float4 g0[5], g1[5];
    int r_[5], c_[5];
#pragma unroll
    for (int it = 0; it < 5; ++it) {
      int ch = tid + it * 512;
      int r = ch / 20, gseg = ch - r * 20;
      int col = gseg * 8;
      r_[it] = r; c_[it] = col;
      const float* src;
      if (col < 64)        src = node_attr + (long)sSrc[r] * DV + col;
      else if (col < 128)  src = node_attr + (long)sDst[r] * DV + (col - 64);
      else                 src = edge_attr + (e0 + r) * DE + (col - 128);
      g0[it] = *(const float4*)src;
      g1[it] = *(const float4*)(src + 4);
    }
#pragma unroll
    for (int it = 0; it < 5; ++it) {
      u16x8 p;
      p[0] = f2bf(g0[it].x); p[1] = f2bf(g0[it].y); p[2] = f2bf(g0[it].z); p[3] = f2bf(g0[it].w);
      p[4] = f2bf(g1[it].x); p[5] = f2bf(g1[it].y); p[6] = f2bf(g1[it].z); p[7] = f2bf(g1[it].w);
      *(u16x8*)&X[r_[it]][c_[it]] = p;
    }
  }

  __syncthreads();

  f32x4 acc[4][2];
#pragma unroll
  for (int rf = 0; rf < 4; ++rf)
#pragma unroll
    for (int cf = 0; cf < 2; ++cf)
#pragma unroll
      for (int j = 0; j < 4; ++j) acc[rf][cf][j] = 0.f;

  // layer 1: [128,160] @ [160,128]  (each wave: 64-row half x 32-col group)
#pragma unroll
  for (int ks = 0; ks < 5; ++ks) {
#pragma unroll
    for (int rf = 0; rf < 4; ++rf) {
      bf16x8 a = *(const bf16x8*)&X[rh + rf * 16 + l15][ks * 32 + lg * 8];
      acc[rf][0] = __builtin_amdgcn_mfma_f32_16x16x32_bf16(a, w1[ks][0], acc[rf][0], 0, 0, 0);
      acc[rf][1] = __builtin_amdgcn_mfma_f32_16x16x32_bf16(a, w1[ks][1], acc[rf][1], 0, 0, 0);
    }
  }

  // load layer-2 weights (overlaps with l1 tail)
  bf16x8 w2[4][2];
  {
    const u16* w2t = wbuf + W2ET_OFF;
#pragma unroll
    for (int cf = 0; cf < 2; ++cf) {
      const u16* p2 = w2t + (wc + cf * 16 + l15) * 128 + lg * 8;
#pragma unroll
      for (int ks = 0; ks < 4; ++ks) w2[ks][cf] = *(const bf16x8*)(p2 + ks * 32);
    }
  }
  float bias2[2] = { b2[wc + l15], b2[wc + 16 + l15] };

#pragma unroll
  for (int rf = 0; rf < 4; ++rf)
#pragma unroll
    for (int cf = 0; cf < 2; ++cf)
#pragma unroll
      for (int j = 0; j < 4; ++j) {
        float hv = acc[rf][cf][j] + bias1[cf];
        hv = hv > 0.f ? hv : 0.f;
        Hs[rh + rf * 16 + lg * 4 + j][wc + cf * 16 + l15] = f2bf(hv);
      }

  __syncthreads();

#pragma unroll
  for (int rf = 0; rf < 4; ++rf)
#pragma unroll
    for (int cf = 0; cf < 2; ++cf)
#pragma unroll
      for (int j = 0; j < 4; ++j) acc[rf][cf][j] = 0.f;

  // layer 2: [128,128] @ [128,128]
#pragma unroll
  for (int ks = 0; ks < 4; ++ks) {
#pragma unroll
    for (int rf = 0; rf < 4; ++rf) {
      bf16x8 a = *(const bf16x8*)&Hs[rh + rf * 16 + l15][ks * 32 + lg * 8];
      acc[rf][0] = __builtin_amdgcn_mfma_f32_16x16x32_bf16(a, w2[ks][0], acc[rf][0], 0, 0, 0);
      acc[rf][1] = __builtin_amdgcn_mfma_f32_16x16x32_bf16(a, w2[ks][1], acc[rf][1], 0, 0, 0);
    }
  }

  __syncthreads();   // Hs reads done before OT overwrite

  float es0 = 0.f, es1 = 0.f;
#pragma unroll
  for (int rf = 0; rf < 4; ++rf) {
#pragma unroll
    for (int cf = 0; cf < 2; ++cf) {
#pragma unroll
      for (int j = 0; j < 4; ++j) {
        float v = acc[rf][cf][j] + bias2[cf];
        OT[rh + rf * 16 + lg * 4 + j][wc + cf * 16 + l15] = v;
        if (cf == 0) es0 += v; else es1 += v;
      }
    }
  }

  __syncthreads();   // OT ready

  // fully contiguous e_out store: 128 consecutive rows = 64KB block
#pragma unroll
  for (int i = 0; i < 8; ++i) {
    int ch = tid + i * 512;
    int r = ch >> 5, c4 = ch & 31;
    float4 f = *(const float4*)&OT[r][c4 * 4];
    *(float4*)(e_out + (e0 + r) * H + c4 * 4) = f;
  }

#pragma unroll
  for (int m = 16; m < 64; m <<= 1) { es0 += __shfl_xor(es0, m); es1 += __shfl_xor(es1, m); }
  if (lane < 16) {
    atomicAdd(&esum_p[(wc + lane) * 16], es0);
    atomicAdd(&esum_p[(wc + 16 + lane) * 16], es1);
  }
}

// ---- node kernel: 64 nodes/block, 512 threads; CSR gather-aggregate in regs ----
__global__ __launch_bounds__(512, 2) void node_kernel(
    const float* __restrict__ node_attr, const u16* __restrict__ wbuf,
    const float* __restrict__ bias_f, const float* __restrict__ b2,
    const float* __restrict__ e_out, const int* __restrict__ offsets,
    const int* __restrict__ cursor, const int* __restrict__ bucket,
    float* __restrict__ v_out, float* __restrict__ vsum_p)
{
  __shared__ __align__(16) u16 X[64][196];    // 192 cols + pad (stride 98 dw)
  __shared__ __align__(16) u16 Hs[64][132];

  const int tid = threadIdx.x;
  const int wave = tid >> 6, lane = tid & 63;
  const int l15 = lane & 15, lg = lane >> 4;
  const int wc = (wave & 3) * 32;
  const int rh = (wave >> 2) * 32;
  const long n0 = (long)blockIdx.x * 64;

  // ---- CSR gather: 8 threads/node, 64B slice each, 2-edge unroll ----
  {
    int gr = tid >> 3, gs = tid & 7;            // node row, 16-float slice
    long gn = n0 + gr; if (gn >= N_NODES) gn = N_NODES - 1;
    float a[16];
#pragma unroll
    for (int k = 0; k < 16; ++k) a[k] = 0.f;
    int s = offsets[gn], e = cursor[gn];
    int i = s;
    for (; i + 2 <= e; i += 2) {
      const float* p0 = e_out + (long)bucket[i] * H + gs * 16;
      const float* p1 = e_out + (long)bucket[i + 1] * H + gs * 16;
      float4 f0[4], f1[4];
#pragma unroll
      for (int k = 0; k < 4; ++k) f0[k] = *(const float4*)(p0 + k * 4);
#pragma unroll
      for (int k = 0; k < 4; ++k) f1[k] = *(const float4*)(p1 + k * 4);
#pragma unroll
      for (int k = 0; k < 4; ++k) {
        a[k * 4 + 0] += f0[k].x + f1[k].x;
        a[k * 4 + 1] += f0[k].y + f1[k].y;
        a[k * 4 + 2] += f0[k].z + f1[k].z;
        a[k * 4 + 3] += f0[k].w + f1[k].w;
      }
    }
    if (i < e) {
      const float* p0 = e_out + (long)bucket[i] * H + gs * 16;
#pragma unroll
      for (int k = 0; k < 4; ++k) {
        float4 f = *(const float4*)(p0 + k * 4);
        a[k * 4 + 0] += f.x; a[k * 4 + 1] += f.y;
        a[k * 4 + 2] += f.z; a[k * 4 + 3] += f.w;
      }
    }
#pragma unroll
    for (int k = 0; k < 2; ++k) {
      u16x8 pk;
#pragma unroll
      for (int j = 0; j < 8; ++j) pk[j] = f2bf(a[k * 8 + j]);
      *(u16x8*)&X[gr][64 + gs * 16 + k * 8] = pk;
    }
  }

  // stage node_attr cols 0..63: 512 chunks, 1/thread
  {
    int r = tid >> 3, col = (tid & 7) * 8;
    long n = n0 + r; if (n >= N_NODES) n = N_NODES - 1;
    const float* src = node_attr + n * DV + col;
    float4 f0 = *(const float4*)src;
    float4 f1 = *(const float4*)(src + 4);
    u16x8 p;
    p[0] = f2bf(f0.x); p[1] = f2bf(f0.y); p[2] = f2bf(f0.z); p[3] = f2bf(f0.w);
    p[4] = f2bf(f1.x); p[5] = f2bf(f1.y); p[6] = f2bf(f1.z); p[7] = f2bf(f1.w);
    *(u16x8*)&X[r][col] = p;
  }

  // per-wave weight slices
  bf16x8 w1[6][2], w2[4][2];
  {
    const u16* w1t = wbuf + W1NT_OFF;
    const u16* w2t = wbuf + W2NT_OFF;
#pragma unroll
    for (int cf = 0; cf < 2; ++cf) {
      const u16* p1 = w1t + (wc + cf * 16 + l15) * 192 + lg * 8;
#pragma unroll
      for (int ks = 0; ks < 6; ++ks) w1[ks][cf] = *(const bf16x8*)(p1 + ks * 32);
      const u16* p2 = w2t + (wc + cf * 16 + l15) * 128 + lg * 8;
#pragma unroll
      for (int ks = 0; ks < 4; ++ks) w2[ks][cf] = *(const bf16x8*)(p2 + ks * 32);
    }
  }

  __syncthreads();

  f32x4 acc[2][2];
#pragma unroll
  for (int rf = 0; rf < 2; ++rf)
#pragma unroll
    for (int cf = 0; cf < 2; ++cf)
#pragma unroll
      for (int j = 0; j < 4; ++j) acc[rf][cf][j] = 0.f;

  // layer 1: [64,192] @ [192,128]  (each wave: 32-row half x 32-col group)
#pragma unroll
  for (int ks = 0; ks < 6; ++ks) {
#pragma unroll
    for (int rf = 0; rf < 2; ++rf) {
      bf16x8 a = *(const bf16x8*)&X[rh + rf * 16 + l15][ks * 32 + lg * 8];
      acc[rf][0] = __builtin_amdgcn_mfma_f32_16x16x32_bf16(a, w1[ks][0], acc[rf][0], 0, 0, 0);
      acc[rf][1] = __builtin_amdgcn_mfma_f32_16x16x32_bf16(a, w1[ks][1], acc[rf][1], 0, 0, 0);
    }
  }

  float bias1[2] = { bias_f[128 + wc + l15], bias_f[128 + wc + 16 + l15] };
#pragma unroll
  for (int rf = 0; rf < 2; ++rf)
#pragma unroll
    for (int cf = 0; cf < 2; ++cf)
#pragma unroll
      for (int j = 0; j < 4; ++j) {
        float hv = acc[rf][cf][j] + bias1[cf];
        hv = hv > 0.f ? hv : 0.f;
        Hs[rh + rf * 16 + lg * 4 + j][wc + cf * 16 + l15] = f2bf(hv);
      }

  __syncthreads();

#pragma unroll
  for (int rf = 0; rf < 2; ++rf)
#pragma unroll
    for (int cf = 0; cf < 2; ++cf)
#pragma unroll
      for (int j = 0; j < 4; ++j) acc[rf][cf][j] = 0.f;

#pragma unroll
  for (int ks = 0; ks < 4; ++ks) {
#pragma unroll
    for (int rf = 0; rf < 2; ++rf) {
      bf16x8 a = *(const bf16x8*)&Hs[rh + rf * 16 + l15][ks * 32 + lg * 8];
      acc[rf][0] = __builtin_amdgcn_mfma_f32_16x16x32_bf16(a, w2[ks][0], acc[rf][0], 0, 0, 0);
      acc[rf][1] = __builtin_amdgcn_mfma_f32_16x16x32_bf16(a, w2[ks][1], acc[rf][1], 0, 0, 0);
    }
  }

  float bias2[2] = { b2[wc + l15], b2[wc + 16 + l15] };
  float vs0 = 0.f, vs1 = 0.f;
#pragma unroll
  for (int rf = 0; rf < 2; ++rf) {
#pragma unroll
    for (int cf = 0; cf < 2; ++cf) {
      int colg = wc + cf * 16 + l15;
#pragma unroll
      for (int j = 0; j < 4; ++j) {
        int r = rh + rf * 16 + lg * 4 + j;
        long n = n0 + r;
        if (n < N_NODES) {
          float v = acc[rf][cf][j] + bias2[cf];
          v_out[n * H + colg] = v;
          if (cf == 0) vs0 += v; else vs1 += v;
        }
      }
    }
  }
#pragma unroll
  for (int m = 16; m < 64; m <<= 1) { vs0 += __shfl_xor(vs0, m); vs1 += __shfl_xor(vs1, m); }
  if (lane < 16) {
    atomicAdd(&vsum_p[(wc + lane) * 16], vs0);
    atomicAdd(&vsum_p[(wc + 16 + lane) * 16], vs1);
  }
}

// ---------------- global kernel: G=1, f32 precision ----------------
__global__ void global_kernel(const float* __restrict__ uattr,
    const float* __restrict__ W1g, const float* __restrict__ b1g,
    const float* __restrict__ W2g, const float* __restrict__ b2g,
    const float* __restrict__ esum_p, const float* __restrict__ vsum_p,
    float* __restrict__ g_out)
{
  __shared__ float gin[288];
  __shared__ float hbuf[128];
  int t = threadIdx.x;   // 128 threads
  gin[t]       = vsum_p[t * 16] * (1.f / (float)N_NODES);
  gin[128 + t] = esum_p[t * 16] * (1.f / (float)N_EDGES);
  if (t < 32) gin[256 + t] = uattr[t];
  __syncthreads();
  float a = b1g[t];
  for (int k = 0; k < 288; ++k) a += gin[k] * W1g[k * H + t];
  hbuf[t] = fmaxf(a, 0.f);
  __syncthreads();
  float b = b2g[t];
  for (int k = 0; k < 128; ++k) b += hbuf[k] * W2g[k * H + t];
  g_out[t] = b;
}

extern "C" void kernel_launch(void* const* d_in, const int* in_sizes, int n_in,
                              void* d_out, int out_size, void* d_ws, size_t ws_size,
                              hipStream_t stream) {
  const float* node_attr = (const float*)d_in[0];
  const int*   edges     = (const int*)d_in[1];
  const float* edge_attr = (const float*)d_in[2];
  const float* uattr     = (const float*)d_in[3];
  const float* W1e = (const float*)d_in[6];  const float* b1e = (const float*)d_in[7];
  const float* W2e = (const float*)d_in[8];  const float* b2e = (const float*)d_in[9];
  const float* W1n = (const float*)d_in[10]; const float* b1n = (const float*)d_in[11];
  const float* W2n = (const float*)d_in[12]; const float* b2n = (const float*)d_in[13];
  const float* W1g = (const float*)d_in[14]; const float* b1g = (const float*)d_in[15];
  const float* W2g = (const float*)d_in[16]; const float* b2g = (const float*)d_in[17];

  float* out   = (float*)d_out;
  float* v_out = out;                                          // [N,H]
  float* e_out = out + (long)N_NODES * H;                      // [E,H]
  float* g_out = out + (long)N_NODES * H + (long)N_EDGES * H;  // [G,H]

  char* ws = (char*)d_ws;
  float* esum_p = (float*)(ws + OFF_ESUM);
  float* vsum_p = (float*)(ws + OFF_VSUM);
  float* bias_f = (float*)(ws + OFF_BIAS);
  int*   part   = (int*)(ws + OFF_PART);
  u16*   wbuf   = (u16*)(ws + OFF_WBUF);
  int*   deg    = (int*)(ws + OFF_DEG);     // cursor: start -> end after fill
  int*   offs   = (int*)(ws + OFF_OFFS);
  int*   buck   = (int*)(ws + OFF_BUCK);

  hipMemsetAsync(ws, 0, 16384, stream);                   // esum_p + vsum_p
  hipMemsetAsync(deg, 0, N_NODES * sizeof(int), stream);  // degrees

  prep_weights<<<WBUF_ELEMS / 256, 256, 0, stream>>>(W1e, W2e, W1n, W2n, wbuf);
  prep_bias<<<1, 128, 0, stream>>>(uattr, W1e, b1e, W1n, b1n, bias_f);
  degree_kernel<<<(N_EDGES + 255) / 256, 256, 0, stream>>>(edges, deg);
  scan_part<<<NPART, 256, 0, stream>>>(deg, part);
  scan_top<<<1, 512, 0, stream>>>(part);
  scan_down<<<NPART, 256, 0, stream>>>(part, deg, offs);
  fill_kernel<<<(N_EDGES + 255) / 256, 256, 0, stream>>>(edges, deg, buck);

  edge_kernel<<<NTILES_E, 512, 0, stream>>>(node_attr, edges, edge_attr, wbuf,
                                            bias_f, b2e, e_out, esum_p);
  node_kernel<<<(N_NODES + 63) / 64, 512, 0, stream>>>(node_attr, wbuf,
                                                       bias_f, b2n,
                                                       e_out, offs, deg, buck,
                                                       v_out, vsum_p);
  global_kernel<<<1, 128, 0, stream>>>(uattr, W1g, b1g, W2g, b2g, esum_p, vsum_p, g_out);
}